// Round 11
// baseline (4990.430 us; speedup 1.0000x reference)
//
#include <hip/hip_runtime.h>

typedef short bf16x8 __attribute__((ext_vector_type(8)));
typedef float f32x4 __attribute__((ext_vector_type(4)));

static constexpr int kT = 512;
static constexpr int kN = 64;
static constexpr int kD = 1024;
static constexpr int kH = 1024;
static constexpr int kG = 4 * kH;  // 4096 gate columns

__device__ __forceinline__ unsigned short f2bf(float f) {
  unsigned u = __builtin_bit_cast(unsigned, f);
  return (unsigned short)((u + 0x7fffu + ((u >> 16) & 1u)) >> 16);  // RNE
}
__device__ __forceinline__ unsigned pack2(float a, float b) {
  return (unsigned)f2bf(a) | ((unsigned)f2bf(b) << 16);
}
__device__ __forceinline__ float fsigmoid(float v) {
  return __builtin_amdgcn_rcpf(1.0f + __expf(-v));
}
__device__ __forceinline__ float ftanh(float v) {
  return 1.0f - 2.0f * __builtin_amdgcn_rcpf(__expf(2.0f * v) + 1.0f);
}

// one-shot coherent 16B load -- ONLY used after a proven flag barrier
// (R4/R5/R7/R10 pattern). NEVER spin on raw-asm loads (R6/R8/R9 livelocked).
__device__ __forceinline__ uint4 gld16_coh_u(unsigned long long a) {
  uint4 r;
  asm volatile("global_load_dwordx4 %0, %1, off sc0 sc1" : "=v"(r) : "v"(a) : "memory");
  return r;
}
// plain cached 16B load (issue-only; readiness via later explicit vmcnt)
__device__ __forceinline__ bf16x8 gld16(unsigned long long a) {
  bf16x8 r;
  asm volatile("global_load_dwordx4 %0, %1, off" : "=v"(r) : "v"(a) : "memory");
  return r;
}

// pre-pass: x fp32 -> bf16 (R2..R10-proven)
__global__ __launch_bounds__(256) void xconv(const float* __restrict__ x,
                                             unsigned short* __restrict__ xbf) {
  const int gid = blockIdx.x * 256 + threadIdx.x;
  const float4* x4 = (const float4*)x;
  uint4* o = (uint4*)xbf;
  for (int i = gid; i < (kN * kT * kD) / 8; i += 2048 * 256) {
    const float4 f0 = x4[2 * i];
    const float4 f1 = x4[2 * i + 1];
    uint4 p;
    p.x = pack2(f0.x, f0.y); p.y = pack2(f0.z, f0.w);
    p.z = pack2(f1.x, f1.y); p.w = pack2(f1.z, f1.w);
    o[i] = p;
  }
}

// ========== tagged exchange + flag fallback (R10 machinery, merged detect/load) ==========
// 256 WGs x 256 threads, 1 WG/CU. WG (dom, ug): batch rows dom*16..+15, hidden
// cols ug*16..+15; Wx+Wh resident in VGPRs, K-split over 4 waves (R5/R10-proven).
// Exchange: every thread publishes its h element as (epoch<<16)|bf16 via
// __hip_atomic_store into a double-buffered hTag array. Consumers FAST-poll the
// data itself with __hip_atomic_load (the only proven spin primitive): all 64
// tags == t+1 means the poll IS the h-load. Bounded (24 iters); on miss, fall
// back to R10's proven flag barrier (producers still drain+flag) + one-shot
// coherent loads -> guaranteed termination, no livelock possible.
// ABA-free: epoch is exact-match; hTag memset each launch (in-graph).
template <bool PRE>
__global__ __launch_bounds__(256, 1)
void lstm_tf(const float* __restrict__ x, const float* __restrict__ h0,
             const float* __restrict__ Wx, const float* __restrict__ Wh,
             const float* __restrict__ bias, float* __restrict__ out,
             unsigned* __restrict__ hTag, unsigned* __restrict__ flags,
             const unsigned short* __restrict__ xbf) {
  __shared__ float ps[2][16 * 320];  // double-buffered partials -> 1 sync/step

  const int tid = threadIdx.x;
  const int bx = blockIdx.x;
  const int dom = (bx & 7) >> 1;                 // 0..3
  const int ug = ((bx >> 3) << 1) | (bx & 1);    // 0..63
  const int wv = tid >> 6;                       // wave 0..3 (K-split)
  const int lane = tid & 63;

  // ---- weight fragments resident in VGPRs (R5-proven layout)
  const int colc = ug * 16 + (lane & 15);
  const int krow = (lane >> 4) * 8;
  const int kb = wv * 256;
  bf16x8 wxf[4][8], whf[4][8];
#pragma unroll
  for (int ct = 0; ct < 4; ++ct) {
#pragma unroll
    for (int ks = 0; ks < 8; ++ks) {
      bf16x8 vx, vh;
#pragma unroll
      for (int e = 0; e < 8; ++e) {
        const size_t k = (size_t)(kb + ks * 32 + krow + e);
        vx[e] = (short)f2bf(Wx[k * kG + ct * kH + colc]);
        vh[e] = (short)f2bf(Wh[k * kG + ct * kH + colc]);
      }
      wxf[ct][ks] = vx;
      whf[ct][ks] = vh;
    }
  }

  // gate identity
  const int n_l = tid >> 4;
  const int j_l = tid & 15;
  const int jg = ug * 16 + j_l;
  const float b_i = bias[jg];
  const float b_f = bias[kH + jg];
  const float b_o = bias[2 * kH + jg];
  const float b_g = bias[3 * kH + jg];
  float c = 0.0f;

  // A-frag / publish identity
  const int arow = lane & 15;
  const int nrow = dom * 16 + arow;
  const unsigned long long xbase0 =
      (unsigned long long)nrow * kT * kD * 2 + (unsigned long long)(kb + krow) * 2;
  const unsigned hrowelem = (unsigned)(nrow * kH + kb + krow);      // consumer base
  const unsigned pubeidx = (unsigned)((dom * 16 + n_l) * kH + jg);  // producer elem

  // flag plumbing (R10-exact)
  unsigned* myflag = flags + (dom * 256 + ug * 4 + wv);
  unsigned* pollp = flags + (dom * 256 + wv * 64 + lane);

  bf16x8 xfrag[8], hfrag[8];

  // ---- prologue: x(0) frags
  if (PRE) {
    const unsigned long long xb = (unsigned long long)xbf + xbase0;
#pragma unroll
    for (int ks = 0; ks < 8; ++ks) xfrag[ks] = gld16(xb + (unsigned)(ks * 64));
    asm volatile("s_waitcnt vmcnt(0)" ::: "memory");
    __builtin_amdgcn_sched_barrier(0);
  } else {
    const float* xr = x + (size_t)nrow * kT * kD + (kb + krow);
#pragma unroll
    for (int ks = 0; ks < 8; ++ks) {
      const float4 f0 = *(const float4*)(xr + ks * 32);
      const float4 f1 = *(const float4*)(xr + ks * 32 + 4);
      bf16x8 v;
      v[0] = (short)f2bf(f0.x); v[1] = (short)f2bf(f0.y);
      v[2] = (short)f2bf(f0.z); v[3] = (short)f2bf(f0.w);
      v[4] = (short)f2bf(f1.x); v[5] = (short)f2bf(f1.y);
      v[6] = (short)f2bf(f1.z); v[7] = (short)f2bf(f1.w);
      xfrag[ks] = v;
    }
  }
  // x-half of step 0
  f32x4 acc[4];
#pragma unroll
  for (int ct = 0; ct < 4; ++ct) acc[ct] = (f32x4){0.f, 0.f, 0.f, 0.f};
#pragma unroll
  for (int ks = 0; ks < 8; ++ks)
#pragma unroll
    for (int ct = 0; ct < 4; ++ct)
      acc[ct] = __builtin_amdgcn_mfma_f32_16x16x32_bf16(xfrag[ks], wxf[ct][ks], acc[ct], 0, 0, 0);
  // h(0) from h0 (fp32 -> bf16, compiler-managed loads/waits)
  {
    const float* hr = h0 + (size_t)nrow * kH + (kb + krow);
#pragma unroll
    for (int ks = 0; ks < 8; ++ks) {
      const float4 f0 = *(const float4*)(hr + ks * 32);
      const float4 f1 = *(const float4*)(hr + ks * 32 + 4);
      bf16x8 v;
      v[0] = (short)f2bf(f0.x); v[1] = (short)f2bf(f0.y);
      v[2] = (short)f2bf(f0.z); v[3] = (short)f2bf(f0.w);
      v[4] = (short)f2bf(f1.x); v[5] = (short)f2bf(f1.y);
      v[6] = (short)f2bf(f1.z); v[7] = (short)f2bf(f1.w);
      hfrag[ks] = v;
    }
  }

  for (int t = 0; t < kT; ++t) {
    // ---- h-half MFMAs (hfrag always in registers at loop top)
#pragma unroll
    for (int ks = 0; ks < 8; ++ks)
#pragma unroll
      for (int ct = 0; ct < 4; ++ct)
        acc[ct] = __builtin_amdgcn_mfma_f32_16x16x32_bf16(hfrag[ks], whf[ct][ks], acc[ct], 0, 0, 0);

    // ---- cross-wave K reduction (double-buffered ps -> single sync per step)
    float* p = ps[t & 1];
#pragma unroll
    for (int ct = 0; ct < 4; ++ct)
      *(f32x4*)&p[(ct * 4 + wv) * 320 + (lane & 15) * 20 + (lane >> 4) * 4] = acc[ct];
    __syncthreads();

    float a4[4];
#pragma unroll
    for (int g = 0; g < 4; ++g) {
      a4[g] = p[(g * 4 + 0) * 320 + j_l * 20 + n_l]
            + p[(g * 4 + 1) * 320 + j_l * 20 + n_l]
            + p[(g * 4 + 2) * 320 + j_l * 20 + n_l]
            + p[(g * 4 + 3) * 320 + j_l * 20 + n_l];
    }
    const float gi = fsigmoid(a4[0] + b_i);
    const float gf = fsigmoid(a4[1] + b_f);
    const float go = fsigmoid(a4[2] + b_o);
    const float gg = ftanh(a4[3] + b_g);
    c = gf * c + gi * gg;
    const float hv = go * ftanh(c);

    if (t < kT - 1) {
      const unsigned tgt = (unsigned)(t + 1);
      unsigned* tbuf = hTag + (tgt & 1) * (unsigned)(kN * kH);

      // ---- publish tagged h(t+1): every thread, one dword (proven primitive)
      __hip_atomic_store(tbuf + pubeidx, (tgt << 16) | (unsigned)f2bf(hv),
                         __ATOMIC_RELAXED, __HIP_MEMORY_SCOPE_AGENT);

      // ---- issue x(t+1) frags, then drain publish+x together
      if (PRE) {
        const unsigned long long xb = (unsigned long long)xbf + xbase0 +
                                      (unsigned long long)(t + 1) * 2048u;
#pragma unroll
        for (int ks = 0; ks < 8; ++ks) xfrag[ks] = gld16(xb + (unsigned)(ks * 64));
      } else {
        const float* xr = x + (size_t)nrow * kT * kD + (size_t)(t + 1) * kD + (kb + krow);
#pragma unroll
        for (int ks = 0; ks < 8; ++ks) {
          const float4 f0 = *(const float4*)(xr + ks * 32);
          const float4 f1 = *(const float4*)(xr + ks * 32 + 4);
          bf16x8 v;
          v[0] = (short)f2bf(f0.x); v[1] = (short)f2bf(f0.y);
          v[2] = (short)f2bf(f0.z); v[3] = (short)f2bf(f0.w);
          v[4] = (short)f2bf(f1.x); v[5] = (short)f2bf(f1.y);
          v[6] = (short)f2bf(f1.z); v[7] = (short)f2bf(f1.w);
          xfrag[ks] = v;
        }
      }
      asm volatile("s_waitcnt vmcnt(0)" ::: "memory");  // publish acked (+x ready)
      __builtin_amdgcn_sched_barrier(0);
      // fallback flag (R10-proven ordering: drain precedes flag)
      if (lane == 0)
        __hip_atomic_store(myflag, tgt, __ATOMIC_RELAXED, __HIP_MEMORY_SCOPE_AGENT);

      __builtin_nontemporal_store(hv, &out[((size_t)(dom * 16 + n_l) * kT + t) * kH + jg]);

      // ---- x-half MFMAs (fills the publish-transit window)
#pragma unroll
      for (int ct = 0; ct < 4; ++ct) acc[ct] = (f32x4){0.f, 0.f, 0.f, 0.f};
#pragma unroll
      for (int ks = 0; ks < 8; ++ks)
#pragma unroll
        for (int ct = 0; ct < 4; ++ct)
          acc[ct] = __builtin_amdgcn_mfma_f32_16x16x32_bf16(xfrag[ks], wxf[ct][ks], acc[ct], 0, 0, 0);

      // ---- FAST PATH: bounded spin on the tagged data itself
      const unsigned* pb = tbuf + hrowelem;
      unsigned tgv[8][8];
      bool got = false;
#pragma unroll 1
      for (int it = 0; it < 24; ++it) {
        unsigned bad = 0;
#pragma unroll
        for (int ks = 0; ks < 8; ++ks)
#pragma unroll
          for (int e = 0; e < 8; ++e) {
            tgv[ks][e] = __hip_atomic_load(pb + ks * 32 + e, __ATOMIC_RELAXED,
                                           __HIP_MEMORY_SCOPE_AGENT);
            bad |= (tgv[ks][e] >> 16) ^ tgt;
          }
        if (__all(bad == 0)) { got = true; break; }
        __builtin_amdgcn_s_sleep(1);
      }

      if (got) {
        // the poll IS the h-load: strip tags into fragments
#pragma unroll
        for (int ks = 0; ks < 8; ++ks) {
          uint4 w;
          w.x = (tgv[ks][0] & 0xFFFFu) | (tgv[ks][1] << 16);
          w.y = (tgv[ks][2] & 0xFFFFu) | (tgv[ks][3] << 16);
          w.z = (tgv[ks][4] & 0xFFFFu) | (tgv[ks][5] << 16);
          w.w = (tgv[ks][6] & 0xFFFFu) | (tgv[ks][7] << 16);
          hfrag[ks] = __builtin_bit_cast(bf16x8, w);
        }
      } else {
        // ---- FALLBACK: R10-proven flag barrier + one-shot coherent loads
        for (;;) {
          const unsigned v = __hip_atomic_load(pollp, __ATOMIC_RELAXED,
                                               __HIP_MEMORY_SCOPE_AGENT);
          if (__all((int)v >= (int)tgt)) break;
          __builtin_amdgcn_s_sleep(1);
        }
        __builtin_amdgcn_sched_barrier(0);
        const unsigned long long hb = (unsigned long long)(tbuf + hrowelem);
        uint4 tg4[16];
#pragma unroll
        for (int ks = 0; ks < 8; ++ks) {
          tg4[2 * ks] = gld16_coh_u(hb + (unsigned)(ks * 128));
          tg4[2 * ks + 1] = gld16_coh_u(hb + (unsigned)(ks * 128 + 16));
        }
        asm volatile("s_waitcnt vmcnt(0)" ::: "memory");
        __builtin_amdgcn_sched_barrier(0);
#pragma unroll
        for (int ks = 0; ks < 8; ++ks) {
          const uint4 a = tg4[2 * ks], b2 = tg4[2 * ks + 1];
          uint4 w;
          w.x = (a.x & 0xFFFFu) | (a.y << 16);
          w.y = (a.z & 0xFFFFu) | (a.w << 16);
          w.z = (b2.x & 0xFFFFu) | (b2.y << 16);
          w.w = (b2.z & 0xFFFFu) | (b2.w << 16);
          hfrag[ks] = __builtin_bit_cast(bf16x8, w);
        }
      }
    } else {
      __builtin_nontemporal_store(hv, &out[((size_t)(dom * 16 + n_l) * kT + t) * kH + jg]);
    }
  }
}

// ======================= launch =======================
extern "C" void kernel_launch(void* const* d_in, const int* in_sizes, int n_in,
                              void* d_out, int out_size, void* d_ws, size_t ws_size,
                              hipStream_t stream) {
  (void)in_sizes; (void)n_in; (void)out_size;
  const float* x  = (const float*)d_in[0];
  const float* h0 = (const float*)d_in[1];
  const float* Wx = (const float*)d_in[2];
  const float* Wh = (const float*)d_in[3];
  const float* b  = (const float*)d_in[4];
  float* out = (float*)d_out;

  // ws: [0,4KB) wave flags | [4KB,+512KB) tagged-h double buffer | then bf16 x
  const size_t o_htag = 4096;
  const size_t o_xbf = o_htag + 524288;
  const size_t need_pre = o_xbf + (size_t)kN * kT * kD * 2;

  unsigned* flags = (unsigned*)d_ws;
  unsigned* hTag = (unsigned*)((char*)d_ws + o_htag);
  unsigned short* xbf = (unsigned short*)((char*)d_ws + o_xbf);

  // reset flags + ALL tags (in-graph, replay-safe: old epochs would alias new)
  hipMemsetAsync(d_ws, 0, o_xbf, stream);

  if (ws_size >= need_pre) {
    hipLaunchKernelGGL(xconv, dim3(2048), dim3(256), 0, stream, x, xbf);
    hipLaunchKernelGGL(HIP_KERNEL_NAME(lstm_tf<true>), dim3(256), dim3(256), 0, stream,
                       x, h0, Wx, Wh, b, out, hTag, flags, xbf);
  } else {
    hipLaunchKernelGGL(HIP_KERNEL_NAME(lstm_tf<false>), dim3(256), dim3(256), 0, stream,
                       x, h0, Wx, Wh, b, out, hTag, flags,
                       (const unsigned short*)nullptr);
  }
}

// Round 13
// 2687.954 us; speedup vs baseline: 1.8566x; 1.8566x over previous
//
#include <hip/hip_runtime.h>

typedef short bf16x8 __attribute__((ext_vector_type(8)));
typedef float f32x4 __attribute__((ext_vector_type(4)));

static constexpr int kT = 512;
static constexpr int kN = 64;
static constexpr int kD = 1024;
static constexpr int kH = 1024;
static constexpr int kG = 4 * kH;  // 4096 gate columns

__device__ __forceinline__ unsigned short f2bf(float f) {
  unsigned u = __builtin_bit_cast(unsigned, f);
  return (unsigned short)((u + 0x7fffu + ((u >> 16) & 1u)) >> 16);  // RNE
}
__device__ __forceinline__ unsigned pack2(float a, float b) {
  return (unsigned)f2bf(a) | ((unsigned)f2bf(b) << 16);
}
__device__ __forceinline__ float fsigmoid(float v) {
  return __builtin_amdgcn_rcpf(1.0f + __expf(-v));
}
__device__ __forceinline__ float ftanh(float v) {
  return 1.0f - 2.0f * __builtin_amdgcn_rcpf(__expf(2.0f * v) + 1.0f);
}

// one-shot coherent 16B load -- ONLY after a proven flag barrier (R4/5/7/10).
// NEVER spin on raw-asm loads (R6/8/9 livelocked); NEVER poll data (R11 flood).
__device__ __forceinline__ bf16x8 gld16_coh(unsigned long long a) {
  bf16x8 r;
  asm volatile("global_load_dwordx4 %0, %1, off sc0 sc1" : "=v"(r) : "v"(a) : "memory");
  return r;
}
// plain cached 16B load (issue-only; readiness via explicit counted vmcnt)
__device__ __forceinline__ bf16x8 gld16(unsigned long long a) {
  bf16x8 r;
  asm volatile("global_load_dwordx4 %0, %1, off" : "=v"(r) : "v"(a) : "memory");
  return r;
}

#define VMCNT(n) do { asm volatile("s_waitcnt vmcnt(" #n ")" ::: "memory"); \
                      __builtin_amdgcn_sched_barrier(0); } while (0)

// pre-pass: x fp32 -> bf16 (R2..R10-proven)
__global__ __launch_bounds__(256) void xconv(const float* __restrict__ x,
                                             unsigned short* __restrict__ xbf) {
  const int gid = blockIdx.x * 256 + threadIdx.x;
  const float4* x4 = (const float4*)x;
  uint4* o = (uint4*)xbf;
  for (int i = gid; i < (kN * kT * kD) / 8; i += 2048 * 256) {
    const float4 f0 = x4[2 * i];
    const float4 f1 = x4[2 * i + 1];
    uint4 p;
    p.x = pack2(f0.x, f0.y); p.y = pack2(f0.z, f0.w);
    p.z = pack2(f1.x, f1.y); p.w = pack2(f1.z, f1.w);
    o[i] = p;
  }
}

// ============== R10 structure + merged drain + per-WG flag + 4-way h-wait ==============
// 256 WGs x 256 threads, 1 WG/CU. WG (dom, ug): batch rows dom*16..+15, hidden
// cols ug*16..+15; Wx+Wh resident in VGPRs, K-split over 4 waves (R5/R10-proven).
// Step edge: publish (paired-dword agent atomics) + out store + x(t+1) issue ->
// ONE vmcnt(0) (merged drain) -> LDS counter; 4th wave stores the WG flag
// (monotonic t+1). Consumer wave wv polls its 16 producer WGs' flags
// (__hip_atomic_load, the only proven spin primitive) -> one-shot coherent
// h loads -> loop-top 4-way counted waits overlap arrival with h-MFMAs.
// WG-granularity flags are dependency-exact: each consumer wave needs all 4
// waves of each of its 16 producer WGs.
template <bool PRE>
__global__ __launch_bounds__(256, 1)
void lstm_fg2(const float* __restrict__ x, const float* __restrict__ h0,
              const float* __restrict__ Wx, const float* __restrict__ Wh,
              const float* __restrict__ bias, float* __restrict__ out,
              unsigned short* __restrict__ hbuf, unsigned* __restrict__ flags,
              const unsigned short* __restrict__ xbf) {
  __shared__ float ps[2][16 * 320];  // double-buffered partials -> 1 sync/step
  __shared__ unsigned wgcnt;         // monotonic per-step wave-arrival counter

  const int tid = threadIdx.x;
  const int bx = blockIdx.x;
  const int dom = (bx & 7) >> 1;                 // 0..3
  const int ug = ((bx >> 3) << 1) | (bx & 1);    // 0..63
  const int wv = tid >> 6;                       // wave 0..3 (K-split)
  const int lane = tid & 63;

  if (tid == 0) wgcnt = 0;  // ordered before first use by the t=0 ps-sync

  // ---- weight fragments resident in VGPRs (R5/R10-proven layout)
  const int colc = ug * 16 + (lane & 15);
  const int krow = (lane >> 4) * 8;
  const int kb = wv * 256;
  bf16x8 wxf[4][8], whf[4][8];
#pragma unroll
  for (int ct = 0; ct < 4; ++ct) {
#pragma unroll
    for (int ks = 0; ks < 8; ++ks) {
      bf16x8 vx, vh;
#pragma unroll
      for (int e = 0; e < 8; ++e) {
        const size_t k = (size_t)(kb + ks * 32 + krow + e);
        vx[e] = (short)f2bf(Wx[k * kG + ct * kH + colc]);
        vh[e] = (short)f2bf(Wh[k * kG + ct * kH + colc]);
      }
      wxf[ct][ks] = vx;
      whf[ct][ks] = vh;
    }
  }

  // gate identity
  const int n_l = tid >> 4;
  const int j_l = tid & 15;
  const int jg = ug * 16 + j_l;
  const float b_i = bias[jg];
  const float b_f = bias[kH + jg];
  const float b_o = bias[2 * kH + jg];
  const float b_g = bias[3 * kH + jg];
  float c = 0.0f;

  // A-frag / publish identity
  const int arow = lane & 15;
  const int nrow = dom * 16 + arow;
  const unsigned long long xbase0 =
      (unsigned long long)nrow * kT * kD * 2 + (unsigned long long)(kb + krow) * 2;
  const unsigned long long hbase0 =
      (unsigned long long)nrow * kH * 2 + (unsigned long long)(kb + krow) * 2;
  const unsigned pubeidx = (unsigned)((dom * 16 + n_l) * kH + jg);

  // flag plumbing: ONE flag per WG; consumer wave wv polls its 16 producers
  unsigned* myflag = flags + (dom * 64 + ug);
  unsigned* pollp = flags + (dom * 64 + wv * 16 + (lane & 15));

  bf16x8 xfrag[8], hfrag[8];

  // ---- prologue: x(0) frags
  if (PRE) {
    const unsigned long long xb = (unsigned long long)xbf + xbase0;
#pragma unroll
    for (int ks = 0; ks < 8; ++ks) xfrag[ks] = gld16(xb + (unsigned)(ks * 64));
    VMCNT(0);
  } else {
    const float* xr = x + (size_t)nrow * kT * kD + (kb + krow);
#pragma unroll
    for (int ks = 0; ks < 8; ++ks) {
      const float4 f0 = *(const float4*)(xr + ks * 32);
      const float4 f1 = *(const float4*)(xr + ks * 32 + 4);
      bf16x8 v;
      v[0] = (short)f2bf(f0.x); v[1] = (short)f2bf(f0.y);
      v[2] = (short)f2bf(f0.z); v[3] = (short)f2bf(f0.w);
      v[4] = (short)f2bf(f1.x); v[5] = (short)f2bf(f1.y);
      v[6] = (short)f2bf(f1.z); v[7] = (short)f2bf(f1.w);
      xfrag[ks] = v;
    }
  }
  // x-half of step 0
  f32x4 acc[4];
#pragma unroll
  for (int ct = 0; ct < 4; ++ct) acc[ct] = (f32x4){0.f, 0.f, 0.f, 0.f};
#pragma unroll
  for (int ks = 0; ks < 8; ++ks)
#pragma unroll
    for (int ct = 0; ct < 4; ++ct)
      acc[ct] = __builtin_amdgcn_mfma_f32_16x16x32_bf16(xfrag[ks], wxf[ct][ks], acc[ct], 0, 0, 0);
  // h(0) from h0 (fp32 -> bf16, compiler-managed loads/waits)
  {
    const float* hr = h0 + (size_t)nrow * kH + (kb + krow);
#pragma unroll
    for (int ks = 0; ks < 8; ++ks) {
      const float4 f0 = *(const float4*)(hr + ks * 32);
      const float4 f1 = *(const float4*)(hr + ks * 32 + 4);
      bf16x8 v;
      v[0] = (short)f2bf(f0.x); v[1] = (short)f2bf(f0.y);
      v[2] = (short)f2bf(f0.z); v[3] = (short)f2bf(f0.w);
      v[4] = (short)f2bf(f1.x); v[5] = (short)f2bf(f1.y);
      v[6] = (short)f2bf(f1.z); v[7] = (short)f2bf(f1.w);
      hfrag[ks] = v;
    }
  }
  VMCNT(0);  // zero ledger entering counted-land (t=0 waits pass trivially)

  for (int t = 0; t < kT; ++t) {
    // ---- h-half MFMAs: 4-way counted waits on the 8 in-flight h loads
    VMCNT(6);
#pragma unroll
    for (int ks = 0; ks < 2; ++ks)
#pragma unroll
      for (int ct = 0; ct < 4; ++ct)
        acc[ct] = __builtin_amdgcn_mfma_f32_16x16x32_bf16(hfrag[ks], whf[ct][ks], acc[ct], 0, 0, 0);
    VMCNT(4);
#pragma unroll
    for (int ks = 2; ks < 4; ++ks)
#pragma unroll
      for (int ct = 0; ct < 4; ++ct)
        acc[ct] = __builtin_amdgcn_mfma_f32_16x16x32_bf16(hfrag[ks], whf[ct][ks], acc[ct], 0, 0, 0);
    VMCNT(2);
#pragma unroll
    for (int ks = 4; ks < 6; ++ks)
#pragma unroll
      for (int ct = 0; ct < 4; ++ct)
        acc[ct] = __builtin_amdgcn_mfma_f32_16x16x32_bf16(hfrag[ks], whf[ct][ks], acc[ct], 0, 0, 0);
    VMCNT(0);
#pragma unroll
    for (int ks = 6; ks < 8; ++ks)
#pragma unroll
      for (int ct = 0; ct < 4; ++ct)
        acc[ct] = __builtin_amdgcn_mfma_f32_16x16x32_bf16(hfrag[ks], whf[ct][ks], acc[ct], 0, 0, 0);

    // ---- cross-wave K reduction (double-buffered ps -> single sync per step)
    float* p = ps[t & 1];
#pragma unroll
    for (int ct = 0; ct < 4; ++ct)
      *(f32x4*)&p[(ct * 4 + wv) * 320 + (lane & 15) * 20 + (lane >> 4) * 4] = acc[ct];
    __syncthreads();

    float a4[4];
#pragma unroll
    for (int g = 0; g < 4; ++g) {
      a4[g] = p[(g * 4 + 0) * 320 + j_l * 20 + n_l]
            + p[(g * 4 + 1) * 320 + j_l * 20 + n_l]
            + p[(g * 4 + 2) * 320 + j_l * 20 + n_l]
            + p[(g * 4 + 3) * 320 + j_l * 20 + n_l];
    }
    const float gi = fsigmoid(a4[0] + b_i);
    const float gf = fsigmoid(a4[1] + b_f);
    const float go = fsigmoid(a4[2] + b_o);
    const float gg = ftanh(a4[3] + b_g);
    c = gf * c + gi * gg;
    const float hv = go * ftanh(c);

    if (t < kT - 1) {
      const unsigned tgt = (unsigned)(t + 1);
      const unsigned buf1 = tgt & 1;

      // ---- publish h(t+1) (paired dword agent atomics) + out + x issue,
      //      then ONE merged drain (saves a full RT vs R10's two drains)
      const unsigned mybf = (unsigned)f2bf(hv);
      const unsigned up = (unsigned)__shfl_xor((int)mybf, 1);
      if ((j_l & 1) == 0) {
        __hip_atomic_store((unsigned*)(hbuf + buf1 * (kN * kH) + pubeidx),
                           mybf | (up << 16), __ATOMIC_RELAXED, __HIP_MEMORY_SCOPE_AGENT);
      }
      __builtin_nontemporal_store(hv, &out[((size_t)(dom * 16 + n_l) * kT + t) * kH + jg]);
      if (PRE) {
        const unsigned long long xb = (unsigned long long)xbf + xbase0 +
                                      (unsigned long long)(t + 1) * 2048u;
#pragma unroll
        for (int ks = 0; ks < 8; ++ks) xfrag[ks] = gld16(xb + (unsigned)(ks * 64));
      }
      VMCNT(0);  // publish acked + out acked + xfrag ready -- one RT

      // ---- WG flag: 4th-arriving wave raises it (LDS atomic, intra-WG)
      if (lane == 0) {
        const unsigned old = atomicAdd(&wgcnt, 1u);
        if (old == 4u * t + 3u)
          __hip_atomic_store(myflag, tgt, __ATOMIC_RELAXED, __HIP_MEMORY_SCOPE_AGENT);
      }

      if (!PRE) {
        const float* xr = x + (size_t)nrow * kT * kD + (size_t)(t + 1) * kD + (kb + krow);
#pragma unroll
        for (int ks = 0; ks < 8; ++ks) {
          const float4 f0 = *(const float4*)(xr + ks * 32);
          const float4 f1 = *(const float4*)(xr + ks * 32 + 4);
          bf16x8 v;
          v[0] = (short)f2bf(f0.x); v[1] = (short)f2bf(f0.y);
          v[2] = (short)f2bf(f0.z); v[3] = (short)f2bf(f0.w);
          v[4] = (short)f2bf(f1.x); v[5] = (short)f2bf(f1.y);
          v[6] = (short)f2bf(f1.z); v[7] = (short)f2bf(f1.w);
          xfrag[ks] = v;
        }
      }
      // ---- x-half MFMAs for t+1 (fills flag transit)
#pragma unroll
      for (int ct = 0; ct < 4; ++ct) acc[ct] = (f32x4){0.f, 0.f, 0.f, 0.f};
#pragma unroll
      for (int ks = 0; ks < 8; ++ks)
#pragma unroll
        for (int ct = 0; ct < 4; ++ct)
          acc[ct] = __builtin_amdgcn_mfma_f32_16x16x32_bf16(xfrag[ks], wxf[ct][ks], acc[ct], 0, 0, 0);

      // ---- poll: lane&15 watches producer WG flag (16 dwords per wave)
      for (;;) {
        const unsigned v = __hip_atomic_load(pollp, __ATOMIC_RELAXED,
                                             __HIP_MEMORY_SCOPE_AGENT);
        if (__all((int)v >= (int)tgt)) break;
        __builtin_amdgcn_s_sleep(1);
      }
      __builtin_amdgcn_sched_barrier(0);

      // ---- one-shot coherent h(t+1) loads (proven post-barrier pattern)
      const unsigned long long hb = (unsigned long long)hbuf +
                                    (unsigned long long)buf1 * (kN * kH * 2) + hbase0;
#pragma unroll
      for (int ks = 0; ks < 8; ++ks) hfrag[ks] = gld16_coh(hb + (unsigned)(ks * 64));
    } else {
      __builtin_nontemporal_store(hv, &out[((size_t)(dom * 16 + n_l) * kT + t) * kH + jg]);
    }
  }
}

// ======================= launch =======================
extern "C" void kernel_launch(void* const* d_in, const int* in_sizes, int n_in,
                              void* d_out, int out_size, void* d_ws, size_t ws_size,
                              hipStream_t stream) {
  (void)in_sizes; (void)n_in; (void)out_size;
  const float* x  = (const float*)d_in[0];
  const float* h0 = (const float*)d_in[1];
  const float* Wx = (const float*)d_in[2];
  const float* Wh = (const float*)d_in[3];
  const float* b  = (const float*)d_in[4];
  float* out = (float*)d_out;

  // ws: [0,4KB) WG flags | [4KB,+256KB) h double buffer | [260KB,+64MB) bf16 x
  const size_t o_hbuf = 4096;
  const size_t o_xbf = o_hbuf + 262144;
  const size_t need_pre = o_xbf + (size_t)kN * kT * kD * 2;

  unsigned* flags = (unsigned*)d_ws;
  unsigned short* hbuf = (unsigned short*)((char*)d_ws + o_hbuf);
  unsigned short* xbf = (unsigned short*)((char*)d_ws + o_xbf);

  hipMemsetAsync(d_ws, 0, 4096, stream);  // reset flags (in-graph, replay-safe)

  if (ws_size >= need_pre) {
    hipLaunchKernelGGL(xconv, dim3(2048), dim3(256), 0, stream, x, xbf);
    hipLaunchKernelGGL(HIP_KERNEL_NAME(lstm_fg2<true>), dim3(256), dim3(256), 0, stream,
                       x, h0, Wx, Wh, b, out, hbuf, flags, xbf);
  } else {
    hipLaunchKernelGGL(HIP_KERNEL_NAME(lstm_fg2<false>), dim3(256), dim3(256), 0, stream,
                       x, h0, Wx, Wh, b, out, hbuf, flags,
                       (const unsigned short*)nullptr);
  }
}

// Round 14
// 2042.926 us; speedup vs baseline: 2.4428x; 1.3157x over previous
//
#include <hip/hip_runtime.h>

typedef short bf16x8 __attribute__((ext_vector_type(8)));
typedef float f32x4 __attribute__((ext_vector_type(4)));

static constexpr int kT = 512;
static constexpr int kN = 64;
static constexpr int kD = 1024;
static constexpr int kH = 1024;
static constexpr int kG = 4 * kH;  // 4096 gate columns

__device__ __forceinline__ unsigned short f2bf(float f) {
  unsigned u = __builtin_bit_cast(unsigned, f);
  return (unsigned short)((u + 0x7fffu + ((u >> 16) & 1u)) >> 16);  // RNE
}
__device__ __forceinline__ unsigned pack2(float a, float b) {
  return (unsigned)f2bf(a) | ((unsigned)f2bf(b) << 16);
}
__device__ __forceinline__ float fsigmoid(float v) {
  return __builtin_amdgcn_rcpf(1.0f + __expf(-v));
}
__device__ __forceinline__ float ftanh(float v) {
  return 1.0f - 2.0f * __builtin_amdgcn_rcpf(__expf(2.0f * v) + 1.0f);
}

// one-shot coherent 16B load -- ONLY after a proven flag barrier (R4/5/7/10).
// NEVER spin on raw-asm loads (R6/8/9 livelocked); NEVER poll data (R11 flood).
__device__ __forceinline__ bf16x8 gld16_coh(unsigned long long a) {
  bf16x8 r;
  asm volatile("global_load_dwordx4 %0, %1, off sc0 sc1" : "=v"(r) : "v"(a) : "memory");
  return r;
}
// plain cached 16B load (issue-only; readiness via explicit counted vmcnt)
__device__ __forceinline__ bf16x8 gld16(unsigned long long a) {
  bf16x8 r;
  asm volatile("global_load_dwordx4 %0, %1, off" : "=v"(r) : "v"(a) : "memory");
  return r;
}

#define VMCNT(n) do { asm volatile("s_waitcnt vmcnt(" #n ")" ::: "memory"); \
                      __builtin_amdgcn_sched_barrier(0); } while (0)

// pre-pass: x fp32 -> bf16 (R2..R10-proven)
__global__ __launch_bounds__(256) void xconv(const float* __restrict__ x,
                                             unsigned short* __restrict__ xbf) {
  const int gid = blockIdx.x * 256 + threadIdx.x;
  const float4* x4 = (const float4*)x;
  uint4* o = (uint4*)xbf;
  for (int i = gid; i < (kN * kT * kD) / 8; i += 2048 * 256) {
    const float4 f0 = x4[2 * i];
    const float4 f1 = x4[2 * i + 1];
    uint4 p;
    p.x = pack2(f0.x, f0.y); p.y = pack2(f0.z, f0.w);
    p.z = pack2(f1.x, f1.y); p.w = pack2(f1.z, f1.w);
    o[i] = p;
  }
}

// ================= R10 structure + counted flag drain + deferred out-store =================
// 256 WGs x 256 threads, 1 WG/CU. WG (dom, ug): batch rows dom*16..+15, hidden
// cols ug*16..+15; Wx+Wh resident in VGPRs, K-split over 4 waves.
// R14 deltas vs R10 (PRE path only; R13 lesson: flag drain set must contain
// ONLY the publish):
//  (1) publish(1 vmem op) -> issue x(8) -> vmcnt(8): in-order retirement proves
//      the publish is acked while x-loads stay in flight -> flag immediately.
//  (2) out-store moved AFTER the x-half MFMAs: its HBM ack retires during
//      poll/h-load/next-step (R10 drained it serially in the x vmcnt(0)).
//  (3) loop-top ledger = [out(1), h(8)]: vmcnt(4) retires {out,h0..h3},
//      vmcnt(0) the rest -- same instructions as R10, re-verified.
template <bool PRE>
__global__ __launch_bounds__(256, 1)
void lstm_fg(const float* __restrict__ x, const float* __restrict__ h0,
             const float* __restrict__ Wx, const float* __restrict__ Wh,
             const float* __restrict__ bias, float* __restrict__ out,
             unsigned short* __restrict__ hbuf, unsigned* __restrict__ flags,
             const unsigned short* __restrict__ xbf) {
  __shared__ float ps[2][16 * 320];  // double-buffered partials -> 1 sync/step

  const int tid = threadIdx.x;
  const int bx = blockIdx.x;
  const int dom = (bx & 7) >> 1;                 // 0..3
  const int ug = ((bx >> 3) << 1) | (bx & 1);    // 0..63
  const int wv = tid >> 6;                       // wave 0..3 (K-split)
  const int lane = tid & 63;

  // ---- weight fragments resident in VGPRs (R5/R10-proven layout)
  const int colc = ug * 16 + (lane & 15);
  const int krow = (lane >> 4) * 8;
  const int kb = wv * 256;
  bf16x8 wxf[4][8], whf[4][8];
#pragma unroll
  for (int ct = 0; ct < 4; ++ct) {
#pragma unroll
    for (int ks = 0; ks < 8; ++ks) {
      bf16x8 vx, vh;
#pragma unroll
      for (int e = 0; e < 8; ++e) {
        const size_t k = (size_t)(kb + ks * 32 + krow + e);
        vx[e] = (short)f2bf(Wx[k * kG + ct * kH + colc]);
        vh[e] = (short)f2bf(Wh[k * kG + ct * kH + colc]);
      }
      wxf[ct][ks] = vx;
      whf[ct][ks] = vh;
    }
  }

  // gate identity
  const int n_l = tid >> 4;
  const int j_l = tid & 15;
  const int jg = ug * 16 + j_l;
  const float b_i = bias[jg];
  const float b_f = bias[kH + jg];
  const float b_o = bias[2 * kH + jg];
  const float b_g = bias[3 * kH + jg];
  float c = 0.0f;

  // A-frag / publish identity
  const int arow = lane & 15;
  const int nrow = dom * 16 + arow;
  const unsigned long long xbase0 =
      (unsigned long long)nrow * kT * kD * 2 + (unsigned long long)(kb + krow) * 2;
  const unsigned long long hbase0 =
      (unsigned long long)nrow * kH * 2 + (unsigned long long)(kb + krow) * 2;
  const unsigned pubeidx = (unsigned)((dom * 16 + n_l) * kH + jg);

  // flag plumbing (R10-exact): producer flag dword + per-lane poll address
  unsigned* myflag = flags + (dom * 256 + ug * 4 + wv);
  unsigned* pollp = flags + (dom * 256 + wv * 64 + lane);

  bf16x8 xfrag[8], hfrag[8];

  // ---- prologue: x(0) frags
  if (PRE) {
    const unsigned long long xb = (unsigned long long)xbf + xbase0;
#pragma unroll
    for (int ks = 0; ks < 8; ++ks) xfrag[ks] = gld16(xb + (unsigned)(ks * 64));
    VMCNT(0);
  } else {
    const float* xr = x + (size_t)nrow * kT * kD + (kb + krow);
#pragma unroll
    for (int ks = 0; ks < 8; ++ks) {
      const float4 f0 = *(const float4*)(xr + ks * 32);
      const float4 f1 = *(const float4*)(xr + ks * 32 + 4);
      bf16x8 v;
      v[0] = (short)f2bf(f0.x); v[1] = (short)f2bf(f0.y);
      v[2] = (short)f2bf(f0.z); v[3] = (short)f2bf(f0.w);
      v[4] = (short)f2bf(f1.x); v[5] = (short)f2bf(f1.y);
      v[6] = (short)f2bf(f1.z); v[7] = (short)f2bf(f1.w);
      xfrag[ks] = v;
    }
  }
  // x-half of step 0
  f32x4 acc[4];
#pragma unroll
  for (int ct = 0; ct < 4; ++ct) acc[ct] = (f32x4){0.f, 0.f, 0.f, 0.f};
#pragma unroll
  for (int ks = 0; ks < 8; ++ks)
#pragma unroll
    for (int ct = 0; ct < 4; ++ct)
      acc[ct] = __builtin_amdgcn_mfma_f32_16x16x32_bf16(xfrag[ks], wxf[ct][ks], acc[ct], 0, 0, 0);
  // h(0) from h0 (fp32 -> bf16, compiler-managed loads/waits)
  {
    const float* hr = h0 + (size_t)nrow * kH + (kb + krow);
#pragma unroll
    for (int ks = 0; ks < 8; ++ks) {
      const float4 f0 = *(const float4*)(hr + ks * 32);
      const float4 f1 = *(const float4*)(hr + ks * 32 + 4);
      bf16x8 v;
      v[0] = (short)f2bf(f0.x); v[1] = (short)f2bf(f0.y);
      v[2] = (short)f2bf(f0.z); v[3] = (short)f2bf(f0.w);
      v[4] = (short)f2bf(f1.x); v[5] = (short)f2bf(f1.y);
      v[6] = (short)f2bf(f1.z); v[7] = (short)f2bf(f1.w);
      hfrag[ks] = v;
    }
  }
  VMCNT(0);  // zero the vmcnt ledger before entering counted-land

  for (int t = 0; t < kT; ++t) {
    // ---- h-half MFMAs; ledger = [out(1), h(8)] for t>0 (0 at t=0: trivial)
    VMCNT(4);   // retires {out, h0..h3}
    __builtin_amdgcn_sched_barrier(0);
#pragma unroll
    for (int ks = 0; ks < 4; ++ks)
#pragma unroll
      for (int ct = 0; ct < 4; ++ct)
        acc[ct] = __builtin_amdgcn_mfma_f32_16x16x32_bf16(hfrag[ks], whf[ct][ks], acc[ct], 0, 0, 0);
    VMCNT(0);   // retires {h4..h7}
#pragma unroll
    for (int ks = 4; ks < 8; ++ks)
#pragma unroll
      for (int ct = 0; ct < 4; ++ct)
        acc[ct] = __builtin_amdgcn_mfma_f32_16x16x32_bf16(hfrag[ks], whf[ct][ks], acc[ct], 0, 0, 0);

    // ---- cross-wave K reduction (double-buffered ps -> single sync per step)
    float* p = ps[t & 1];
#pragma unroll
    for (int ct = 0; ct < 4; ++ct)
      *(f32x4*)&p[(ct * 4 + wv) * 320 + (lane & 15) * 20 + (lane >> 4) * 4] = acc[ct];
    __syncthreads();

    float a4[4];
#pragma unroll
    for (int g = 0; g < 4; ++g) {
      a4[g] = p[(g * 4 + 0) * 320 + j_l * 20 + n_l]
            + p[(g * 4 + 1) * 320 + j_l * 20 + n_l]
            + p[(g * 4 + 2) * 320 + j_l * 20 + n_l]
            + p[(g * 4 + 3) * 320 + j_l * 20 + n_l];
    }
    const float gi = fsigmoid(a4[0] + b_i);
    const float gf = fsigmoid(a4[1] + b_f);
    const float go = fsigmoid(a4[2] + b_o);
    const float gg = ftanh(a4[3] + b_g);
    c = gf * c + gi * gg;
    const float hv = go * ftanh(c);

    if (t < kT - 1) {
      const unsigned tgt = (unsigned)(t + 1);
      const unsigned buf1 = tgt & 1;
      const unsigned mybf = (unsigned)f2bf(hv);
      const unsigned up = (unsigned)__shfl_xor((int)mybf, 1);

      if (PRE) {
        // (1) publish -> x issue -> vmcnt(8): publish acked, x still in flight
        if ((j_l & 1) == 0) {
          __hip_atomic_store((unsigned*)(hbuf + buf1 * (kN * kH) + pubeidx),
                             mybf | (up << 16), __ATOMIC_RELAXED, __HIP_MEMORY_SCOPE_AGENT);
        }
        const unsigned long long xb = (unsigned long long)xbf + xbase0 +
                                      (unsigned long long)(t + 1) * 2048u;
#pragma unroll
        for (int ks = 0; ks < 8; ++ks) xfrag[ks] = gld16(xb + (unsigned)(ks * 64));
        VMCNT(8);   // ledger [pub, x*8] -> retires pub only
        if (lane == 0)
          __hip_atomic_store(myflag, tgt, __ATOMIC_RELAXED, __HIP_MEMORY_SCOPE_AGENT);
        VMCNT(0);   // x ready (pub already retired; nothing else outstanding)
      } else {
        // conservative R10 sequence (untested fallback path, compiler loads)
        if ((j_l & 1) == 0) {
          __hip_atomic_store((unsigned*)(hbuf + buf1 * (kN * kH) + pubeidx),
                             mybf | (up << 16), __ATOMIC_RELAXED, __HIP_MEMORY_SCOPE_AGENT);
        }
        VMCNT(0);
        if (lane == 0)
          __hip_atomic_store(myflag, tgt, __ATOMIC_RELAXED, __HIP_MEMORY_SCOPE_AGENT);
        const float* xr = x + (size_t)nrow * kT * kD + (size_t)(t + 1) * kD + (kb + krow);
#pragma unroll
        for (int ks = 0; ks < 8; ++ks) {
          const float4 f0 = *(const float4*)(xr + ks * 32);
          const float4 f1 = *(const float4*)(xr + ks * 32 + 4);
          bf16x8 v;
          v[0] = (short)f2bf(f0.x); v[1] = (short)f2bf(f0.y);
          v[2] = (short)f2bf(f0.z); v[3] = (short)f2bf(f0.w);
          v[4] = (short)f2bf(f1.x); v[5] = (short)f2bf(f1.y);
          v[6] = (short)f2bf(f1.z); v[7] = (short)f2bf(f1.w);
          xfrag[ks] = v;
        }
      }

      // ---- x-half MFMAs for t+1 (fills the flag-transit window)
#pragma unroll
      for (int ct = 0; ct < 4; ++ct) acc[ct] = (f32x4){0.f, 0.f, 0.f, 0.f};
#pragma unroll
      for (int ks = 0; ks < 8; ++ks)
#pragma unroll
        for (int ct = 0; ct < 4; ++ct)
          acc[ct] = __builtin_amdgcn_mfma_f32_16x16x32_bf16(xfrag[ks], wxf[ct][ks], acc[ct], 0, 0, 0);

      // (2) out-store HERE: ack retires under poll + h-load + next step edge
      __builtin_amdgcn_sched_barrier(0);  // pin: no hoist above the MFMAs
      __builtin_nontemporal_store(hv, &out[((size_t)(dom * 16 + n_l) * kT + t) * kH + jg]);

      // ---- fine-grained poll: lane l watches producer-wave flag l (R10-exact)
      for (;;) {
        const unsigned v = __hip_atomic_load(pollp, __ATOMIC_RELAXED,
                                             __HIP_MEMORY_SCOPE_AGENT);
        if (__all((int)v >= (int)tgt)) break;
        __builtin_amdgcn_s_sleep(1);
      }
      __builtin_amdgcn_sched_barrier(0);

      // ---- one-shot coherent h(t+1) loads (proven post-barrier pattern)
      const unsigned long long hb = (unsigned long long)hbuf +
                                    (unsigned long long)buf1 * (kN * kH * 2) + hbase0;
#pragma unroll
      for (int ks = 0; ks < 8; ++ks) hfrag[ks] = gld16_coh(hb + (unsigned)(ks * 64));
    } else {
      __builtin_nontemporal_store(hv, &out[((size_t)(dom * 16 + n_l) * kT + t) * kH + jg]);
    }
  }
}

// ======================= launch =======================
extern "C" void kernel_launch(void* const* d_in, const int* in_sizes, int n_in,
                              void* d_out, int out_size, void* d_ws, size_t ws_size,
                              hipStream_t stream) {
  (void)in_sizes; (void)n_in; (void)out_size;
  const float* x  = (const float*)d_in[0];
  const float* h0 = (const float*)d_in[1];
  const float* Wx = (const float*)d_in[2];
  const float* Wh = (const float*)d_in[3];
  const float* b  = (const float*)d_in[4];
  float* out = (float*)d_out;

  // ws: [0,4KB) wave flags | [4KB,+256KB) h double buffer | [260KB,+64MB) bf16 x
  const size_t o_hbuf = 4096;
  const size_t o_xbf = o_hbuf + 262144;
  const size_t need_pre = o_xbf + (size_t)kN * kT * kD * 2;

  unsigned* flags = (unsigned*)d_ws;
  unsigned short* hbuf = (unsigned short*)((char*)d_ws + o_hbuf);
  unsigned short* xbf = (unsigned short*)((char*)d_ws + o_xbf);

  hipMemsetAsync(d_ws, 0, 4096, stream);  // reset flags (in-graph, replay-safe)

  if (ws_size >= need_pre) {
    hipLaunchKernelGGL(xconv, dim3(2048), dim3(256), 0, stream, x, xbf);
    hipLaunchKernelGGL(HIP_KERNEL_NAME(lstm_fg<true>), dim3(256), dim3(256), 0, stream,
                       x, h0, Wx, Wh, b, out, hbuf, flags, xbf);
  } else {
    hipLaunchKernelGGL(HIP_KERNEL_NAME(lstm_fg<false>), dim3(256), dim3(256), 0, stream,
                       x, h0, Wx, Wh, b, out, hbuf, flags,
                       (const unsigned short*)nullptr);
  }
}